// Round 1
// baseline (135.956 us; speedup 1.0000x reference)
//
#include <hip/hip_runtime.h>
#include <math.h>

#define CIN 256
#define COUT 768   // 3 * OUTC
#define OUTC 256
#define HH 64
#define WW 64
#define HW 4096

// ---------------------------------------------------------------------------
// Kernel 1: QKV projection. qkv[n][d][p] = sum_c w[d][c] * x[n][c][p] + b[d]
// Per batch: GEMM M=768 (d), N=4096 (pixels), K=256. fp32 vector ALU
// (no fp32 MFMA on CDNA4). 128x128 tile, BK=16, 256 threads, 8x8 micro-tile.
// ---------------------------------------------------------------------------
__global__ __launch_bounds__(256) void qkv_gemm_kernel(
    const float* __restrict__ x, const float* __restrict__ wq,
    const float* __restrict__ bq, float* __restrict__ qkv)
{
    __shared__ float Ws[16][132];  // [k][d]  (+4 pad, keeps 16B alignment)
    __shared__ float Xs[16][132];  // [k][p]

    const int n  = blockIdx.z;
    const int d0 = blockIdx.y * 128;
    const int p0 = blockIdx.x * 128;
    const int tid = threadIdx.x;
    const int ty = tid >> 4;   // 0..15 -> d sub-block
    const int tx = tid & 15;   // 0..15 -> p sub-block
    const float* xb = x + (size_t)n * CIN * HW;

    float acc[8][8];
    #pragma unroll
    for (int i = 0; i < 8; ++i)
        #pragma unroll
        for (int j = 0; j < 8; ++j) acc[i][j] = 0.f;

    const int wrow = tid >> 1;         // 0..127 (d offset)
    const int wcol = (tid & 1) * 8;    // 0 or 8 (c offset)
    const int xrow = tid >> 4;         // 0..15  (c offset)
    const int xcol = (tid & 15) * 8;   // 0..120 (p offset)

    for (int k0 = 0; k0 < CIN; k0 += 16) {
        const float4 wv0 = *(const float4*)(&wq[(size_t)(d0 + wrow) * CIN + k0 + wcol]);
        const float4 wv1 = *(const float4*)(&wq[(size_t)(d0 + wrow) * CIN + k0 + wcol + 4]);
        const float4 xv0 = *(const float4*)(&xb[(size_t)(k0 + xrow) * HW + p0 + xcol]);
        const float4 xv1 = *(const float4*)(&xb[(size_t)(k0 + xrow) * HW + p0 + xcol + 4]);

        // W tile stored transposed: Ws[c][d]
        Ws[wcol + 0][wrow] = wv0.x;
        Ws[wcol + 1][wrow] = wv0.y;
        Ws[wcol + 2][wrow] = wv0.z;
        Ws[wcol + 3][wrow] = wv0.w;
        Ws[wcol + 4][wrow] = wv1.x;
        Ws[wcol + 5][wrow] = wv1.y;
        Ws[wcol + 6][wrow] = wv1.z;
        Ws[wcol + 7][wrow] = wv1.w;
        *(float4*)(&Xs[xrow][xcol])     = xv0;
        *(float4*)(&Xs[xrow][xcol + 4]) = xv1;
        __syncthreads();

        #pragma unroll
        for (int k = 0; k < 16; ++k) {
            float4 a0 = *(const float4*)(&Ws[k][ty * 8]);
            float4 a1 = *(const float4*)(&Ws[k][ty * 8 + 4]);
            float4 b0 = *(const float4*)(&Xs[k][tx * 8]);
            float4 b1 = *(const float4*)(&Xs[k][tx * 8 + 4]);
            float av[8] = {a0.x, a0.y, a0.z, a0.w, a1.x, a1.y, a1.z, a1.w};
            float bv[8] = {b0.x, b0.y, b0.z, b0.w, b1.x, b1.y, b1.z, b1.w};
            #pragma unroll
            for (int i = 0; i < 8; ++i)
                #pragma unroll
                for (int j = 0; j < 8; ++j)
                    acc[i][j] = fmaf(av[i], bv[j], acc[i][j]);
        }
        __syncthreads();
    }

    float* ob = qkv + (size_t)n * COUT * HW;
    #pragma unroll
    for (int i = 0; i < 8; ++i) {
        const int d = d0 + ty * 8 + i;
        const float bias = bq[d];
        float4 o0 = make_float4(acc[i][0] + bias, acc[i][1] + bias,
                                acc[i][2] + bias, acc[i][3] + bias);
        float4 o1 = make_float4(acc[i][4] + bias, acc[i][5] + bias,
                                acc[i][6] + bias, acc[i][7] + bias);
        *(float4*)(&ob[(size_t)d * HW + p0 + tx * 8])     = o0;
        *(float4*)(&ob[(size_t)d * HW + p0 + tx * 8 + 4]) = o1;
    }
}

// ---------------------------------------------------------------------------
// Kernel 2: 5x5 neighborhood attention. One thread per (n, head, h, w).
// q[32] in regs; 25 scores; softmax; PV accumulate. All d-plane loads are
// coalesced across the 64-wide w dimension; K/V reuse served by L1/L2/L3
// (qkv = 48 MB < 256 MB Infinity Cache).
// ---------------------------------------------------------------------------
__global__ __launch_bounds__(256) void attn_kernel(
    const float* __restrict__ qkv, float* __restrict__ out)
{
    const int n    = blockIdx.z;
    const int head = blockIdx.y;
    const int h = blockIdx.x * 4 + (threadIdx.x >> 6);
    const int w = threadIdx.x & 63;
    const int p = h * WW + w;

    const float* Qb = qkv + ((size_t)n * COUT + head * 32) * HW;
    const float* Kb = Qb + (size_t)OUTC * HW;
    const float* Vb = Qb + (size_t)2 * OUTC * HW;

    float q[32];
    #pragma unroll
    for (int d = 0; d < 32; ++d) q[d] = Qb[(size_t)d * HW + p];

    float sc[25];
    #pragma unroll
    for (int ky = 0; ky < 5; ++ky) {
        const int hh = h + ky - 2;
        #pragma unroll
        for (int kx = 0; kx < 5; ++kx) {
            const int ww = w + kx - 2;
            float s = -1e30f;
            if (hh >= 0 && hh < HH && ww >= 0 && ww < WW) {
                const int pp = hh * WW + ww;
                float a = 0.f;
                #pragma unroll
                for (int d = 0; d < 32; ++d)
                    a = fmaf(q[d], Kb[(size_t)d * HW + pp], a);
                s = a;
            }
            sc[ky * 5 + kx] = s;
        }
    }

    float m = sc[0];
    #pragma unroll
    for (int k = 1; k < 25; ++k) m = fmaxf(m, sc[k]);
    float sum = 0.f;
    #pragma unroll
    for (int k = 0; k < 25; ++k) {
        float e = __expf(sc[k] - m);   // masked: exp(-1e30) -> 0
        sc[k] = e;
        sum += e;
    }
    const float inv = 1.f / sum;

    float acc[32];
    #pragma unroll
    for (int d = 0; d < 32; ++d) acc[d] = 0.f;
    #pragma unroll
    for (int ky = 0; ky < 5; ++ky) {
        const int hh = h + ky - 2;
        if (hh < 0 || hh >= HH) continue;
        #pragma unroll
        for (int kx = 0; kx < 5; ++kx) {
            const int ww = w + kx - 2;
            if (ww < 0 || ww >= WW) continue;
            const float a = sc[ky * 5 + kx];
            const int pp = hh * WW + ww;
            #pragma unroll
            for (int d = 0; d < 32; ++d)
                acc[d] = fmaf(a, Vb[(size_t)d * HW + pp], acc[d]);
        }
    }

    float* Ob = out + ((size_t)n * OUTC + head * 32) * HW;
    #pragma unroll
    for (int d = 0; d < 32; ++d) Ob[(size_t)d * HW + p] = acc[d] * inv;
}

// ---------------------------------------------------------------------------
extern "C" void kernel_launch(void* const* d_in, const int* in_sizes, int n_in,
                              void* d_out, int out_size, void* d_ws, size_t ws_size,
                              hipStream_t stream) {
    const float* x  = (const float*)d_in[0];   // (4, 256, 64, 64)
    const float* wq = (const float*)d_in[1];   // (768, 256)
    const float* bq = (const float*)d_in[2];   // (768,)
    float* out = (float*)d_out;                // (4, 256, 64, 64)
    float* qkv = (float*)d_ws;                 // (4, 768, 64, 64) = 48 MB scratch

    dim3 g1(HW / 128, COUT / 128, 4);          // (32, 6, 4)
    qkv_gemm_kernel<<<g1, 256, 0, stream>>>(x, wq, bq, qkv);

    dim3 g2(HH / 4, 8, 4);                     // (16, 8, 4)
    attn_kernel<<<g2, 256, 0, stream>>>(qkv, out);
}

// Round 2
// 52.479 us; speedup vs baseline: 2.5907x; 2.5907x over previous
//
#include <hip/hip_runtime.h>
#include <hip/hip_bf16.h>
#include <math.h>

#define CIN 256
#define COUT 768   // 3 * OUTC
#define OUTC 256
#define HH 64
#define WW 64
#define HW 4096

typedef unsigned int uint32;
typedef unsigned short ushort16;

using short8 = __attribute__((ext_vector_type(8))) short;
using f32x4  = __attribute__((ext_vector_type(4))) float;

// pack 2 fp32 -> 2 bf16 (RTNE) in one dword (a = low 16, b = high 16)
__device__ inline uint32 pkbf2(float a, float b) {
    __hip_bfloat162 h = __float22bfloat162_rn(make_float2(a, b));
    union { __hip_bfloat162 h2; uint32 u; } cv; cv.h2 = h;
    return cv.u;
}

__device__ inline float bflo(uint32 u) { return __uint_as_float(u << 16); }
__device__ inline float bfhi(uint32 u) { return __uint_as_float(u & 0xffff0000u); }

// ---------------------------------------------------------------------------
// Kernel 1: QKV projection, bf16 MFMA.
// C[d, p] = sum_c W[d,c] * X[c,p] + b[d]; per batch M=768, N=4096, K=256.
// Output layout: qkv_bf16[n][slot=d>>5][p][dlow=d&31]  (slot = 3*8 head-groups)
// Block: 128x128 tile, 256 threads (4 waves 2x2, 64x64 each), BK=32,
// reg-staged fp32->bf16 conversion, T14 prefetch (next loads before MFMA).
// ---------------------------------------------------------------------------
#define LDSTR 40   // shorts per LDS row (32 + 8 pad; 80 B = 20 dw, odd*4 -> uniform banks)

__global__ __launch_bounds__(256) void qkv_gemm_kernel(
    const float* __restrict__ x, const float* __restrict__ wq,
    const float* __restrict__ bq, ushort16* __restrict__ qkv)
{
    __shared__ ushort16 As[128 * LDSTR];  // [d-row][k]
    __shared__ ushort16 Bs[128 * LDSTR];  // [p-col][k]

    const int n   = blockIdx.z;
    const int d0  = blockIdx.y * 128;
    const int p0  = blockIdx.x * 128;
    const int tid = threadIdx.x;
    const int lane = tid & 63;
    const int wid  = tid >> 6;
    const int wm = wid >> 1;     // wave m index (0..1)
    const int wn = wid & 1;      // wave n index (0..1)

    const float* xb = x + (size_t)n * CIN * HW;

    // ---- staging assignments ----
    // A: thread handles chunks c=tid and c=tid+256: row = c>>2 (so +64 for 2nd),
    //    k-offset = (c&3)*8  (8 contiguous k)
    const int arow = tid >> 2;
    const int akk  = (tid & 3) * 8;
    const float* aptr = wq + (size_t)(d0 + arow) * CIN + akk;
    // B: thread handles one 8k x 2p chunk: kg = tid>>6 (k-offset 8*kg), pg = tid&63 (p = 2*pg)
    const int bkg = (tid >> 6) * 8;
    const int bpg = (tid & 63) * 2;
    const float* bptr = xb + (size_t)bkg * HW + p0 + bpg;

    ushort16* awr0 = (ushort16*)&As[arow * LDSTR + akk];
    ushort16* awr1 = (ushort16*)&As[(arow + 64) * LDSTR + akk];
    ushort16* bwr0 = (ushort16*)&Bs[bpg * LDSTR + bkg];
    ushort16* bwr1 = (ushort16*)&Bs[(bpg + 1) * LDSTR + bkg];

    f32x4 acc[4][4];
    #pragma unroll
    for (int i = 0; i < 4; ++i)
        #pragma unroll
        for (int j = 0; j < 4; ++j) acc[i][j] = (f32x4){0.f, 0.f, 0.f, 0.f};

    // staging registers (fp32, live across the MFMA phase for latency hiding)
    float4 a_st[4];   // 2 chunks x 8 floats
    float2 b_st[8];   // 8 k-rows x 2 p

    // prologue: issue loads for kt = 0
    {
        a_st[0] = *(const float4*)(aptr);
        a_st[1] = *(const float4*)(aptr + 4);
        a_st[2] = *(const float4*)(aptr + (size_t)64 * CIN);
        a_st[3] = *(const float4*)(aptr + (size_t)64 * CIN + 4);
        #pragma unroll
        for (int j = 0; j < 8; ++j)
            b_st[j] = *(const float2*)(bptr + (size_t)j * HW);
    }

    const int lrow = lane & 15;
    const int lk   = (lane >> 4) * 8;

    #pragma unroll 1
    for (int kt = 0; kt < 8; ++kt) {
        __syncthreads();   // previous MFMA phase done reading LDS

        // convert + write LDS (data dep stalls on the prefetched loads)
        {
            uint32 w0 = pkbf2(a_st[0].x, a_st[0].y), w1 = pkbf2(a_st[0].z, a_st[0].w);
            uint32 w2 = pkbf2(a_st[1].x, a_st[1].y), w3 = pkbf2(a_st[1].z, a_st[1].w);
            *(uint4*)awr0 = make_uint4(w0, w1, w2, w3);
            w0 = pkbf2(a_st[2].x, a_st[2].y); w1 = pkbf2(a_st[2].z, a_st[2].w);
            w2 = pkbf2(a_st[3].x, a_st[3].y); w3 = pkbf2(a_st[3].z, a_st[3].w);
            *(uint4*)awr1 = make_uint4(w0, w1, w2, w3);
            uint4 c0, c1;
            c0.x = pkbf2(b_st[0].x, b_st[1].x); c0.y = pkbf2(b_st[2].x, b_st[3].x);
            c0.z = pkbf2(b_st[4].x, b_st[5].x); c0.w = pkbf2(b_st[6].x, b_st[7].x);
            c1.x = pkbf2(b_st[0].y, b_st[1].y); c1.y = pkbf2(b_st[2].y, b_st[3].y);
            c1.z = pkbf2(b_st[4].y, b_st[5].y); c1.w = pkbf2(b_st[6].y, b_st[7].y);
            *(uint4*)bwr0 = c0;
            *(uint4*)bwr1 = c1;
        }

        // prefetch next K-tile while MFMA runs
        if (kt < 7) {
            const int ko = (kt + 1) * 32;
            a_st[0] = *(const float4*)(aptr + ko);
            a_st[1] = *(const float4*)(aptr + ko + 4);
            a_st[2] = *(const float4*)(aptr + (size_t)64 * CIN + ko);
            a_st[3] = *(const float4*)(aptr + (size_t)64 * CIN + ko + 4);
            #pragma unroll
            for (int j = 0; j < 8; ++j)
                b_st[j] = *(const float2*)(bptr + (size_t)(ko + j) * HW);
        }

        __syncthreads();   // LDS tile visible

        short8 af[4], bf[4];
        #pragma unroll
        for (int fm = 0; fm < 4; ++fm)
            af[fm] = *(const short8*)&As[(wm * 64 + fm * 16 + lrow) * LDSTR + lk];
        #pragma unroll
        for (int fn = 0; fn < 4; ++fn)
            bf[fn] = *(const short8*)&Bs[(wn * 64 + fn * 16 + lrow) * LDSTR + lk];
        #pragma unroll
        for (int fm = 0; fm < 4; ++fm)
            #pragma unroll
            for (int fn = 0; fn < 4; ++fn)
                acc[fm][fn] = __builtin_amdgcn_mfma_f32_16x16x32_bf16(
                    af[fm], bf[fn], acc[fm][fn], 0, 0, 0);
    }

    // epilogue: bias + cvt bf16 + store to [n][slot][p][dlow]
    const int hi4 = lane >> 4;          // 0..3
    ushort16* qn = qkv + (size_t)n * COUT * HW;
    #pragma unroll
    for (int fm = 0; fm < 4; ++fm) {
        const int D = d0 + wm * 64 + fm * 16 + hi4 * 4;   // rows D..D+3
        const float4 bias = *(const float4*)(&bq[D]);
        const int slot = D >> 5, dlow = D & 31;
        ushort16* qs = qn + (size_t)slot * (HW * 32) + dlow;
        #pragma unroll
        for (int fn = 0; fn < 4; ++fn) {
            const int p = p0 + wn * 64 + fn * 16 + lrow;
            f32x4 v = acc[fm][fn];
            uint32 u0 = pkbf2(v[0] + bias.x, v[1] + bias.y);
            uint32 u1 = pkbf2(v[2] + bias.z, v[3] + bias.w);
            *(uint2*)(qs + (size_t)p * 32) = make_uint2(u0, u1);
        }
    }
}

// ---------------------------------------------------------------------------
// Kernel 2: 5x5 neighborhood attention on packed bf16 qkv.
// Layout in: [n][slot24][p4096][d32] bf16; slot = {Q:0-7, K:8-15, V:16-23}+head.
// One thread per (n, head, h, w); fp32 math; 4x uint4 per K/V vector.
// ---------------------------------------------------------------------------
__global__ __launch_bounds__(256) void attn_kernel(
    const ushort16* __restrict__ qkv, float* __restrict__ out)
{
    const int n    = blockIdx.z;
    const int head = blockIdx.y;
    const int h = blockIdx.x * 4 + (threadIdx.x >> 6);
    const int w = threadIdx.x & 63;
    const int p = h * WW + w;

    const ushort16* Qp = qkv + (((size_t)(n * 24 + head)) * HW + p) * 32;
    const ushort16* Kb = qkv + ((size_t)(n * 24 + 8 + head)) * HW * 32;
    const ushort16* Vb = qkv + ((size_t)(n * 24 + 16 + head)) * HW * 32;

    float ql[16], qh[16];
    {
        const uint4* Q4 = (const uint4*)Qp;
        #pragma unroll
        for (int i = 0; i < 4; ++i) {
            uint4 u = Q4[i];
            ql[4*i+0] = bflo(u.x); qh[4*i+0] = bfhi(u.x);
            ql[4*i+1] = bflo(u.y); qh[4*i+1] = bfhi(u.y);
            ql[4*i+2] = bflo(u.z); qh[4*i+2] = bfhi(u.z);
            ql[4*i+3] = bflo(u.w); qh[4*i+3] = bfhi(u.w);
        }
    }

    float sc[25];
    #pragma unroll
    for (int ky = 0; ky < 5; ++ky) {
        const int hh = h + ky - 2;
        #pragma unroll
        for (int kx = 0; kx < 5; ++kx) {
            const int ww = w + kx - 2;
            float s = -1e30f;
            if (hh >= 0 && hh < HH && ww >= 0 && ww < WW) {
                const int pp = hh * WW + ww;
                const uint4* K4 = (const uint4*)(Kb + (size_t)pp * 32);
                float a = 0.f;
                #pragma unroll
                for (int i = 0; i < 4; ++i) {
                    uint4 u = K4[i];
                    a = fmaf(ql[4*i+0], bflo(u.x), a); a = fmaf(qh[4*i+0], bfhi(u.x), a);
                    a = fmaf(ql[4*i+1], bflo(u.y), a); a = fmaf(qh[4*i+1], bfhi(u.y), a);
                    a = fmaf(ql[4*i+2], bflo(u.z), a); a = fmaf(qh[4*i+2], bfhi(u.z), a);
                    a = fmaf(ql[4*i+3], bflo(u.w), a); a = fmaf(qh[4*i+3], bfhi(u.w), a);
                }
                s = a;
            }
            sc[ky * 5 + kx] = s;
        }
    }

    float m = sc[0];
    #pragma unroll
    for (int k = 1; k < 25; ++k) m = fmaxf(m, sc[k]);
    float sum = 0.f;
    #pragma unroll
    for (int k = 0; k < 25; ++k) {
        float e = __expf(sc[k] - m);
        sc[k] = e;
        sum += e;
    }
    const float inv = 1.f / sum;

    float al[16], ah[16];
    #pragma unroll
    for (int i = 0; i < 16; ++i) { al[i] = 0.f; ah[i] = 0.f; }
    #pragma unroll
    for (int ky = 0; ky < 5; ++ky) {
        const int hh = h + ky - 2;
        if (hh < 0 || hh >= HH) continue;
        #pragma unroll
        for (int kx = 0; kx < 5; ++kx) {
            const int ww = w + kx - 2;
            if (ww < 0 || ww >= WW) continue;
            const float a = sc[ky * 5 + kx];
            const int pp = hh * WW + ww;
            const uint4* V4 = (const uint4*)(Vb + (size_t)pp * 32);
            #pragma unroll
            for (int i = 0; i < 4; ++i) {
                uint4 u = V4[i];
                al[4*i+0] = fmaf(a, bflo(u.x), al[4*i+0]); ah[4*i+0] = fmaf(a, bfhi(u.x), ah[4*i+0]);
                al[4*i+1] = fmaf(a, bflo(u.y), al[4*i+1]); ah[4*i+1] = fmaf(a, bfhi(u.y), ah[4*i+1]);
                al[4*i+2] = fmaf(a, bflo(u.z), al[4*i+2]); ah[4*i+2] = fmaf(a, bfhi(u.z), ah[4*i+2]);
                al[4*i+3] = fmaf(a, bflo(u.w), al[4*i+3]); ah[4*i+3] = fmaf(a, bfhi(u.w), ah[4*i+3]);
            }
        }
    }

    float* Ob = out + ((size_t)(n * 8 + head) * 32) * HW + p;
    #pragma unroll
    for (int i = 0; i < 16; ++i) {
        Ob[(size_t)(2*i) * HW]     = al[i] * inv;
        Ob[(size_t)(2*i+1) * HW]   = ah[i] * inv;
    }
}

// ---------------------------------------------------------------------------
extern "C" void kernel_launch(void* const* d_in, const int* in_sizes, int n_in,
                              void* d_out, int out_size, void* d_ws, size_t ws_size,
                              hipStream_t stream) {
    const float* x  = (const float*)d_in[0];   // (4, 256, 64, 64)
    const float* wq = (const float*)d_in[1];   // (768, 256)
    const float* bq = (const float*)d_in[2];   // (768,)
    float* out = (float*)d_out;                // (4, 256, 64, 64) fp32
    ushort16* qkv = (ushort16*)d_ws;           // bf16 [4][24][4096][32] = 25 MB

    dim3 g1(HW / 128, COUT / 128, 4);          // (32, 6, 4)
    qkv_gemm_kernel<<<g1, 256, 0, stream>>>(x, wq, bq, qkv);

    dim3 g2(HH / 4, 8, 4);                     // (16, 8, 4)
    attn_kernel<<<g2, 256, 0, stream>>>(qkv, out);
}

// Round 3
// 45.888 us; speedup vs baseline: 2.9628x; 1.1436x over previous
//
#include <hip/hip_runtime.h>
#include <hip/hip_bf16.h>
#include <math.h>

#define CIN 256
#define COUT 768   // 3 * OUTC
#define OUTC 256
#define HH 64
#define WW 64
#define HW 4096

typedef unsigned int uint32;
typedef unsigned short ushort16;

using short8 = __attribute__((ext_vector_type(8))) short;
using f32x4  = __attribute__((ext_vector_type(4))) float;

// pack 2 fp32 -> 2 bf16 (RTNE) in one dword (a = low 16, b = high 16)
__device__ inline uint32 pkbf2(float a, float b) {
    __hip_bfloat162 h = __float22bfloat162_rn(make_float2(a, b));
    union { __hip_bfloat162 h2; uint32 u; } cv; cv.h2 = h;
    return cv.u;
}

__device__ inline float bflo(uint32 u) { return __uint_as_float(u << 16); }
__device__ inline float bfhi(uint32 u) { return __uint_as_float(u & 0xffff0000u); }

// ---------------------------------------------------------------------------
// Kernel 1: QKV projection, bf16 MFMA (unchanged from round 2).
// Output layout: qkv_bf16[n][slot=d>>5][p][dlow=d&31]
// ---------------------------------------------------------------------------
#define LDSTR 40   // shorts per LDS row (32 + 8 pad)

__global__ __launch_bounds__(256) void qkv_gemm_kernel(
    const float* __restrict__ x, const float* __restrict__ wq,
    const float* __restrict__ bq, ushort16* __restrict__ qkv)
{
    __shared__ ushort16 As[128 * LDSTR];  // [d-row][k]
    __shared__ ushort16 Bs[128 * LDSTR];  // [p-col][k]

    const int n   = blockIdx.z;
    const int d0  = blockIdx.y * 128;
    const int p0  = blockIdx.x * 128;
    const int tid = threadIdx.x;
    const int lane = tid & 63;
    const int wid  = tid >> 6;
    const int wm = wid >> 1;
    const int wn = wid & 1;

    const float* xb = x + (size_t)n * CIN * HW;

    const int arow = tid >> 2;
    const int akk  = (tid & 3) * 8;
    const float* aptr = wq + (size_t)(d0 + arow) * CIN + akk;
    const int bkg = (tid >> 6) * 8;
    const int bpg = (tid & 63) * 2;
    const float* bptr = xb + (size_t)bkg * HW + p0 + bpg;

    ushort16* awr0 = (ushort16*)&As[arow * LDSTR + akk];
    ushort16* awr1 = (ushort16*)&As[(arow + 64) * LDSTR + akk];
    ushort16* bwr0 = (ushort16*)&Bs[bpg * LDSTR + bkg];
    ushort16* bwr1 = (ushort16*)&Bs[(bpg + 1) * LDSTR + bkg];

    f32x4 acc[4][4];
    #pragma unroll
    for (int i = 0; i < 4; ++i)
        #pragma unroll
        for (int j = 0; j < 4; ++j) acc[i][j] = (f32x4){0.f, 0.f, 0.f, 0.f};

    float4 a_st[4];
    float2 b_st[8];

    {
        a_st[0] = *(const float4*)(aptr);
        a_st[1] = *(const float4*)(aptr + 4);
        a_st[2] = *(const float4*)(aptr + (size_t)64 * CIN);
        a_st[3] = *(const float4*)(aptr + (size_t)64 * CIN + 4);
        #pragma unroll
        for (int j = 0; j < 8; ++j)
            b_st[j] = *(const float2*)(bptr + (size_t)j * HW);
    }

    const int lrow = lane & 15;
    const int lk   = (lane >> 4) * 8;

    #pragma unroll 1
    for (int kt = 0; kt < 8; ++kt) {
        __syncthreads();

        {
            uint32 w0 = pkbf2(a_st[0].x, a_st[0].y), w1 = pkbf2(a_st[0].z, a_st[0].w);
            uint32 w2 = pkbf2(a_st[1].x, a_st[1].y), w3 = pkbf2(a_st[1].z, a_st[1].w);
            *(uint4*)awr0 = make_uint4(w0, w1, w2, w3);
            w0 = pkbf2(a_st[2].x, a_st[2].y); w1 = pkbf2(a_st[2].z, a_st[2].w);
            w2 = pkbf2(a_st[3].x, a_st[3].y); w3 = pkbf2(a_st[3].z, a_st[3].w);
            *(uint4*)awr1 = make_uint4(w0, w1, w2, w3);
            uint4 c0, c1;
            c0.x = pkbf2(b_st[0].x, b_st[1].x); c0.y = pkbf2(b_st[2].x, b_st[3].x);
            c0.z = pkbf2(b_st[4].x, b_st[5].x); c0.w = pkbf2(b_st[6].x, b_st[7].x);
            c1.x = pkbf2(b_st[0].y, b_st[1].y); c1.y = pkbf2(b_st[2].y, b_st[3].y);
            c1.z = pkbf2(b_st[4].y, b_st[5].y); c1.w = pkbf2(b_st[6].y, b_st[7].y);
            *(uint4*)bwr0 = c0;
            *(uint4*)bwr1 = c1;
        }

        if (kt < 7) {
            const int ko = (kt + 1) * 32;
            a_st[0] = *(const float4*)(aptr + ko);
            a_st[1] = *(const float4*)(aptr + ko + 4);
            a_st[2] = *(const float4*)(aptr + (size_t)64 * CIN + ko);
            a_st[3] = *(const float4*)(aptr + (size_t)64 * CIN + ko + 4);
            #pragma unroll
            for (int j = 0; j < 8; ++j)
                b_st[j] = *(const float2*)(bptr + (size_t)(ko + j) * HW);
        }

        __syncthreads();

        short8 af[4], bf[4];
        #pragma unroll
        for (int fm = 0; fm < 4; ++fm)
            af[fm] = *(const short8*)&As[(wm * 64 + fm * 16 + lrow) * LDSTR + lk];
        #pragma unroll
        for (int fn = 0; fn < 4; ++fn)
            bf[fn] = *(const short8*)&Bs[(wn * 64 + fn * 16 + lrow) * LDSTR + lk];
        #pragma unroll
        for (int fm = 0; fm < 4; ++fm)
            #pragma unroll
            for (int fn = 0; fn < 4; ++fn)
                acc[fm][fn] = __builtin_amdgcn_mfma_f32_16x16x32_bf16(
                    af[fm], bf[fn], acc[fm][fn], 0, 0, 0);
    }

    const int hi4 = lane >> 4;
    ushort16* qn = qkv + (size_t)n * COUT * HW;
    #pragma unroll
    for (int fm = 0; fm < 4; ++fm) {
        const int D = d0 + wm * 64 + fm * 16 + hi4 * 4;
        const float4 bias = *(const float4*)(&bq[D]);
        const int slot = D >> 5, dlow = D & 31;
        ushort16* qs = qn + (size_t)slot * (HW * 32) + dlow;
        #pragma unroll
        for (int fn = 0; fn < 4; ++fn) {
            const int p = p0 + wn * 64 + fn * 16 + lrow;
            f32x4 v = acc[fm][fn];
            uint32 u0 = pkbf2(v[0] + bias.x, v[1] + bias.y);
            uint32 u1 = pkbf2(v[2] + bias.z, v[3] + bias.w);
            *(uint2*)(qs + (size_t)p * 32) = make_uint2(u0, u1);
        }
    }
}

// ---------------------------------------------------------------------------
// Kernel 2: 5x5 neighborhood attention, LDS-staged K/V, 2-thread d-split.
// Block: 256 threads = 4 rows x 32 cols x 2 halves. Tile (n, head, 4h, 32w).
// LDS: K + V halo tile 8 rows x 36 cols x 32d bf16, XOR-swizzled:
//   16B-unit index = (pix*4 + i) ^ (pix & 7)   -> conflict-free at 64B stride.
// Each thread owns 16 of 32 dims; QK partial dot combined via shfl_xor(1).
// ---------------------------------------------------------------------------
#define TR 4          // tile rows
#define TC 32         // tile cols
#define HR 8          // halo rows (TR + 4)
#define HC 36         // halo cols (TC + 4)
#define NPIX (HR*HC)  // 288

__global__ __launch_bounds__(256) void attn_kernel(
    const ushort16* __restrict__ qkv, float* __restrict__ out)
{
    __shared__ uint4 Ks[NPIX * 4];   // 18 KB
    __shared__ uint4 Vs[NPIX * 4];   // 18 KB

    const int n    = blockIdx.z;
    const int head = blockIdx.y;
    const int ht = blockIdx.x >> 1;
    const int wt = blockIdx.x & 1;
    const int h0 = ht * TR;
    const int w0 = wt * TC;

    const int tid  = threadIdx.x;
    const int half = tid & 1;         // which 16 dims
    const int wc   = (tid >> 1) & 31; // col in tile
    const int tr   = tid >> 6;        // row in tile

    const int h = h0 + tr, w = w0 + wc;
    const int p = h * WW + w;

    const uint4* Kb = (const uint4*)(qkv + ((size_t)(n * 24 + 8 + head)) * HW * 32);
    const uint4* Vb = (const uint4*)(qkv + ((size_t)(n * 24 + 16 + head)) * HW * 32);

    // ---- stage K and V halo tiles into LDS (swizzled) ----
    for (int c = tid; c < 2 * NPIX * 4; c += 256) {
        const int b  = (c >= NPIX * 4);
        const int cc = c - b * NPIX * 4;
        const int pix = cc >> 2, i = cc & 3;
        const int hr = pix / HC, cw = pix - hr * HC;
        const int hh = h0 + hr - 2, ww = w0 + cw - 2;
        if (hh >= 0 && hh < HH && ww >= 0 && ww < WW) {
            const int pp = hh * WW + ww;
            const uint4 v = (b ? Vb : Kb)[(size_t)pp * 4 + i];
            const int unit = (pix * 4 + i) ^ (pix & 7);
            (b ? Vs : Ks)[unit] = v;
        }
    }

    // Q: this thread's 16 dims (2 uint4), unpacked to fp32
    float ql[8], qh[8];
    {
        const uint4* Qp = (const uint4*)(qkv + (((size_t)(n * 24 + head)) * HW + p) * 32);
        #pragma unroll
        for (int i = 0; i < 2; ++i) {
            uint4 u = Qp[half * 2 + i];
            ql[4*i+0] = bflo(u.x); qh[4*i+0] = bfhi(u.x);
            ql[4*i+1] = bflo(u.y); qh[4*i+1] = bfhi(u.y);
            ql[4*i+2] = bflo(u.z); qh[4*i+2] = bfhi(u.z);
            ql[4*i+3] = bflo(u.w); qh[4*i+3] = bfhi(u.w);
        }
    }

    __syncthreads();

    // ---- scores: partial dot over 16 dims, combine across the d-pair ----
    float sc[25];
    #pragma unroll
    for (int ky = 0; ky < 5; ++ky) {
        const int hh = h + ky - 2;
        const int hr = tr + ky;
        #pragma unroll
        for (int kx = 0; kx < 5; ++kx) {
            const int ww = w + kx - 2;
            float s;
            if (hh >= 0 && hh < HH && ww >= 0 && ww < WW) {
                const int pix = hr * HC + (wc + kx);
                const int u0 = (pix * 4 + half * 2)     ^ (pix & 7);
                const int u1 = (pix * 4 + half * 2 + 1) ^ (pix & 7);
                uint4 a = Ks[u0], b = Ks[u1];
                float t = 0.f;
                t = fmaf(ql[0], bflo(a.x), t); t = fmaf(qh[0], bfhi(a.x), t);
                t = fmaf(ql[1], bflo(a.y), t); t = fmaf(qh[1], bfhi(a.y), t);
                t = fmaf(ql[2], bflo(a.z), t); t = fmaf(qh[2], bfhi(a.z), t);
                t = fmaf(ql[3], bflo(a.w), t); t = fmaf(qh[3], bfhi(a.w), t);
                t = fmaf(ql[4], bflo(b.x), t); t = fmaf(qh[4], bfhi(b.x), t);
                t = fmaf(ql[5], bflo(b.y), t); t = fmaf(qh[5], bfhi(b.y), t);
                t = fmaf(ql[6], bflo(b.z), t); t = fmaf(qh[6], bfhi(b.z), t);
                t = fmaf(ql[7], bflo(b.w), t); t = fmaf(qh[7], bfhi(b.w), t);
                s = t;
            } else {
                s = -1e30f;
            }
            sc[ky * 5 + kx] = s;
        }
    }
    // combine halves: lanes (2k, 2k+1) hold partials of the same pixel
    #pragma unroll
    for (int k = 0; k < 25; ++k) {
        float o = __shfl_xor(sc[k], 1, 64);
        sc[k] = (sc[k] <= -1e29f) ? sc[k] : sc[k] + o;
    }

    float m = sc[0];
    #pragma unroll
    for (int k = 1; k < 25; ++k) m = fmaxf(m, sc[k]);
    float sum = 0.f;
    #pragma unroll
    for (int k = 0; k < 25; ++k) {
        float e = __expf(sc[k] - m);
        sc[k] = e;
        sum += e;
    }
    const float inv = 1.f / sum;

    // ---- PV: accumulate this thread's 16 dims ----
    float al[8], ah[8];
    #pragma unroll
    for (int i = 0; i < 8; ++i) { al[i] = 0.f; ah[i] = 0.f; }
    #pragma unroll
    for (int ky = 0; ky < 5; ++ky) {
        const int hh = h + ky - 2;
        if (hh < 0 || hh >= HH) continue;
        const int hr = tr + ky;
        #pragma unroll
        for (int kx = 0; kx < 5; ++kx) {
            const int ww = w + kx - 2;
            if (ww < 0 || ww >= WW) continue;
            const float a = sc[ky * 5 + kx];
            const int pix = hr * HC + (wc + kx);
            const int u0 = (pix * 4 + half * 2)     ^ (pix & 7);
            const int u1 = (pix * 4 + half * 2 + 1) ^ (pix & 7);
            uint4 x = Vs[u0], y = Vs[u1];
            al[0] = fmaf(a, bflo(x.x), al[0]); ah[0] = fmaf(a, bfhi(x.x), ah[0]);
            al[1] = fmaf(a, bflo(x.y), al[1]); ah[1] = fmaf(a, bfhi(x.y), ah[1]);
            al[2] = fmaf(a, bflo(x.z), al[2]); ah[2] = fmaf(a, bfhi(x.z), ah[2]);
            al[3] = fmaf(a, bflo(x.w), al[3]); ah[3] = fmaf(a, bfhi(x.w), ah[3]);
            al[4] = fmaf(a, bflo(y.x), al[4]); ah[4] = fmaf(a, bfhi(y.x), ah[4]);
            al[5] = fmaf(a, bflo(y.y), al[5]); ah[5] = fmaf(a, bfhi(y.y), ah[5]);
            al[6] = fmaf(a, bflo(y.z), al[6]); ah[6] = fmaf(a, bfhi(y.z), ah[6]);
            al[7] = fmaf(a, bflo(y.w), al[7]); ah[7] = fmaf(a, bfhi(y.w), ah[7]);
        }
    }

    // ---- store: dims half*16 .. half*16+15 ----
    float* Ob = out + ((size_t)(n * 8 + head) * 32 + half * 16) * HW + p;
    #pragma unroll
    for (int i = 0; i < 8; ++i) {
        Ob[(size_t)(2*i)   * HW] = al[i] * inv;
        Ob[(size_t)(2*i+1) * HW] = ah[i] * inv;
    }
}

// ---------------------------------------------------------------------------
extern "C" void kernel_launch(void* const* d_in, const int* in_sizes, int n_in,
                              void* d_out, int out_size, void* d_ws, size_t ws_size,
                              hipStream_t stream) {
    const float* x  = (const float*)d_in[0];   // (4, 256, 64, 64)
    const float* wq = (const float*)d_in[1];   // (768, 256)
    const float* bq = (const float*)d_in[2];   // (768,)
    float* out = (float*)d_out;                // (4, 256, 64, 64) fp32
    ushort16* qkv = (ushort16*)d_ws;           // bf16 [4][24][4096][32] = 25 MB

    dim3 g1(HW / 128, COUT / 128, 4);          // (32, 6, 4)
    qkv_gemm_kernel<<<g1, 256, 0, stream>>>(x, wq, bq, qkv);

    dim3 g2(32, 8, 4);                         // (16 h-tiles x 2 w-tiles, 8 heads, 4 n)
    attn_kernel<<<g2, 256, 0, stream>>>(qkv, out);
}

// Round 4
// 45.773 us; speedup vs baseline: 2.9702x; 1.0025x over previous
//
#include <hip/hip_runtime.h>
#include <hip/hip_bf16.h>
#include <math.h>

#define CIN 256
#define COUT 768   // 3 * OUTC
#define OUTC 256
#define HH 64
#define WW 64
#define HW 4096

typedef unsigned int uint32;
typedef unsigned short ushort16;

using short8 = __attribute__((ext_vector_type(8))) short;
using f32x4  = __attribute__((ext_vector_type(4))) float;

// pack 2 fp32 -> 2 bf16 (RTNE) in one dword (a = low 16, b = high 16)
__device__ inline uint32 pkbf2(float a, float b) {
    __hip_bfloat162 h = __float22bfloat162_rn(make_float2(a, b));
    union { __hip_bfloat162 h2; uint32 u; } cv; cv.h2 = h;
    return cv.u;
}

// pack 2 fp32 -> 2 fp16 (RTNE via _Float16 cast) in one dword
__device__ inline uint32 pkhf2(float a, float b) {
    union { _Float16 h[2]; uint32 u; } cv;
    cv.h[0] = (_Float16)a; cv.h[1] = (_Float16)b;
    return cv.u;
}

// fp16 halves of a dword -> fp32 (pattern matches v_fma_mix / v_cvt_f32_f16)
__device__ inline float f16lo(uint32 u) {
    union { uint32 u; _Float16 h[2]; } c; c.u = u; return (float)c.h[0];
}
__device__ inline float f16hi(uint32 u) {
    union { uint32 u; _Float16 h[2]; } c; c.u = u; return (float)c.h[1];
}

// lane^1 exchange on the VALU pipe (DPP quad_perm [1,0,3,2]), not LDS
__device__ inline float dpp_xor1(float x) {
#if __has_builtin(__builtin_amdgcn_update_dpp)
    int i = __builtin_amdgcn_update_dpp(0, __float_as_int(x),
                                        0xB1 /*quad_perm 1,0,3,2*/, 0xF, 0xF, true);
    return __int_as_float(i);
#else
    return __shfl_xor(x, 1, 64);
#endif
}

// ---------------------------------------------------------------------------
// Kernel 1: QKV projection, bf16 MFMA (unchanged; epilogue now emits fp16).
// Output layout: qkv_f16[n][slot=d>>5][p][dlow=d&31]
// ---------------------------------------------------------------------------
#define LDSTR 40   // shorts per LDS row (32 + 8 pad)

__global__ __launch_bounds__(256) void qkv_gemm_kernel(
    const float* __restrict__ x, const float* __restrict__ wq,
    const float* __restrict__ bq, ushort16* __restrict__ qkv)
{
    __shared__ ushort16 As[128 * LDSTR];  // [d-row][k]
    __shared__ ushort16 Bs[128 * LDSTR];  // [p-col][k]

    const int n   = blockIdx.z;
    const int d0  = blockIdx.y * 128;
    const int p0  = blockIdx.x * 128;
    const int tid = threadIdx.x;
    const int lane = tid & 63;
    const int wid  = tid >> 6;
    const int wm = wid >> 1;
    const int wn = wid & 1;

    const float* xb = x + (size_t)n * CIN * HW;

    const int arow = tid >> 2;
    const int akk  = (tid & 3) * 8;
    const float* aptr = wq + (size_t)(d0 + arow) * CIN + akk;
    const int bkg = (tid >> 6) * 8;
    const int bpg = (tid & 63) * 2;
    const float* bptr = xb + (size_t)bkg * HW + p0 + bpg;

    ushort16* awr0 = (ushort16*)&As[arow * LDSTR + akk];
    ushort16* awr1 = (ushort16*)&As[(arow + 64) * LDSTR + akk];
    ushort16* bwr0 = (ushort16*)&Bs[bpg * LDSTR + bkg];
    ushort16* bwr1 = (ushort16*)&Bs[(bpg + 1) * LDSTR + bkg];

    f32x4 acc[4][4];
    #pragma unroll
    for (int i = 0; i < 4; ++i)
        #pragma unroll
        for (int j = 0; j < 4; ++j) acc[i][j] = (f32x4){0.f, 0.f, 0.f, 0.f};

    float4 a_st[4];
    float2 b_st[8];

    {
        a_st[0] = *(const float4*)(aptr);
        a_st[1] = *(const float4*)(aptr + 4);
        a_st[2] = *(const float4*)(aptr + (size_t)64 * CIN);
        a_st[3] = *(const float4*)(aptr + (size_t)64 * CIN + 4);
        #pragma unroll
        for (int j = 0; j < 8; ++j)
            b_st[j] = *(const float2*)(bptr + (size_t)j * HW);
    }

    const int lrow = lane & 15;
    const int lk   = (lane >> 4) * 8;

    #pragma unroll 1
    for (int kt = 0; kt < 8; ++kt) {
        __syncthreads();

        {
            uint32 w0 = pkbf2(a_st[0].x, a_st[0].y), w1 = pkbf2(a_st[0].z, a_st[0].w);
            uint32 w2 = pkbf2(a_st[1].x, a_st[1].y), w3 = pkbf2(a_st[1].z, a_st[1].w);
            *(uint4*)awr0 = make_uint4(w0, w1, w2, w3);
            w0 = pkbf2(a_st[2].x, a_st[2].y); w1 = pkbf2(a_st[2].z, a_st[2].w);
            w2 = pkbf2(a_st[3].x, a_st[3].y); w3 = pkbf2(a_st[3].z, a_st[3].w);
            *(uint4*)awr1 = make_uint4(w0, w1, w2, w3);
            uint4 c0, c1;
            c0.x = pkbf2(b_st[0].x, b_st[1].x); c0.y = pkbf2(b_st[2].x, b_st[3].x);
            c0.z = pkbf2(b_st[4].x, b_st[5].x); c0.w = pkbf2(b_st[6].x, b_st[7].x);
            c1.x = pkbf2(b_st[0].y, b_st[1].y); c1.y = pkbf2(b_st[2].y, b_st[3].y);
            c1.z = pkbf2(b_st[4].y, b_st[5].y); c1.w = pkbf2(b_st[6].y, b_st[7].y);
            *(uint4*)bwr0 = c0;
            *(uint4*)bwr1 = c1;
        }

        if (kt < 7) {
            const int ko = (kt + 1) * 32;
            a_st[0] = *(const float4*)(aptr + ko);
            a_st[1] = *(const float4*)(aptr + ko + 4);
            a_st[2] = *(const float4*)(aptr + (size_t)64 * CIN + ko);
            a_st[3] = *(const float4*)(aptr + (size_t)64 * CIN + ko + 4);
            #pragma unroll
            for (int j = 0; j < 8; ++j)
                b_st[j] = *(const float2*)(bptr + (size_t)(ko + j) * HW);
        }

        __syncthreads();

        short8 af[4], bf[4];
        #pragma unroll
        for (int fm = 0; fm < 4; ++fm)
            af[fm] = *(const short8*)&As[(wm * 64 + fm * 16 + lrow) * LDSTR + lk];
        #pragma unroll
        for (int fn = 0; fn < 4; ++fn)
            bf[fn] = *(const short8*)&Bs[(wn * 64 + fn * 16 + lrow) * LDSTR + lk];
        #pragma unroll
        for (int fm = 0; fm < 4; ++fm)
            #pragma unroll
            for (int fn = 0; fn < 4; ++fn)
                acc[fm][fn] = __builtin_amdgcn_mfma_f32_16x16x32_bf16(
                    af[fm], bf[fn], acc[fm][fn], 0, 0, 0);
    }

    const int hi4 = lane >> 4;
    ushort16* qn = qkv + (size_t)n * COUT * HW;
    #pragma unroll
    for (int fm = 0; fm < 4; ++fm) {
        const int D = d0 + wm * 64 + fm * 16 + hi4 * 4;
        const float4 bias = *(const float4*)(&bq[D]);
        const int slot = D >> 5, dlow = D & 31;
        ushort16* qs = qn + (size_t)slot * (HW * 32) + dlow;
        #pragma unroll
        for (int fn = 0; fn < 4; ++fn) {
            const int p = p0 + wn * 64 + fn * 16 + lrow;
            f32x4 v = acc[fm][fn];
            uint32 u0 = pkhf2(v[0] + bias.x, v[1] + bias.y);
            uint32 u1 = pkhf2(v[2] + bias.z, v[3] + bias.w);
            *(uint2*)(qs + (size_t)p * 32) = make_uint2(u0, u1);
        }
    }
}

// ---------------------------------------------------------------------------
// Kernel 2: 5x5 neighborhood attention, LDS-staged K/V (fp16), 2-thread
// d-split, DPP score combine, fma_mix-pattern f16 math.
// ---------------------------------------------------------------------------
#define TR 4          // tile rows
#define TC 32         // tile cols
#define HR 8          // halo rows (TR + 4)
#define HC 36         // halo cols (TC + 4)
#define NPIX (HR*HC)  // 288

__global__ __launch_bounds__(256) void attn_kernel(
    const ushort16* __restrict__ qkv, float* __restrict__ out)
{
    __shared__ uint4 Ks[NPIX * 4];   // 18 KB
    __shared__ uint4 Vs[NPIX * 4];   // 18 KB

    const int n    = blockIdx.z;
    const int head = blockIdx.y;
    const int ht = blockIdx.x >> 1;
    const int wt = blockIdx.x & 1;
    const int h0 = ht * TR;
    const int w0 = wt * TC;

    const int tid  = threadIdx.x;
    const int half = tid & 1;         // which 16 dims
    const int wc   = (tid >> 1) & 31; // col in tile
    const int tr   = tid >> 6;        // row in tile

    const int h = h0 + tr, w = w0 + wc;
    const int p = h * WW + w;

    const uint4* Kb = (const uint4*)(qkv + ((size_t)(n * 24 + 8 + head)) * HW * 32);
    const uint4* Vb = (const uint4*)(qkv + ((size_t)(n * 24 + 16 + head)) * HW * 32);

    // ---- stage K and V halo tiles into LDS (swizzled) ----
    for (int c = tid; c < 2 * NPIX * 4; c += 256) {
        const int b  = (c >= NPIX * 4);
        const int cc = c - b * NPIX * 4;
        const int pix = cc >> 2, i = cc & 3;
        const int hr = pix / HC, cw = pix - hr * HC;
        const int hh = h0 + hr - 2, ww = w0 + cw - 2;
        if (hh >= 0 && hh < HH && ww >= 0 && ww < WW) {
            const int pp = hh * WW + ww;
            const uint4 v = (b ? Vb : Kb)[(size_t)pp * 4 + i];
            const int unit = (pix * 4 + i) ^ (pix & 7);
            (b ? Vs : Ks)[unit] = v;
        }
    }

    // Q: this thread's 16 dims as fp32
    float qf[16];
    {
        const uint4* Qp = (const uint4*)(qkv + (((size_t)(n * 24 + head)) * HW + p) * 32);
        #pragma unroll
        for (int i = 0; i < 2; ++i) {
            uint4 u = Qp[half * 2 + i];
            qf[8*i+0] = f16lo(u.x); qf[8*i+1] = f16hi(u.x);
            qf[8*i+2] = f16lo(u.y); qf[8*i+3] = f16hi(u.y);
            qf[8*i+4] = f16lo(u.z); qf[8*i+5] = f16hi(u.z);
            qf[8*i+6] = f16lo(u.w); qf[8*i+7] = f16hi(u.w);
        }
    }

    __syncthreads();

    // ---- scores: partial dot over 16 dims, combine across the d-pair ----
    float sc[25];
    #pragma unroll
    for (int ky = 0; ky < 5; ++ky) {
        const int hh = h + ky - 2;
        const int hr = tr + ky;
        #pragma unroll
        for (int kx = 0; kx < 5; ++kx) {
            const int ww = w + kx - 2;
            float s;
            if (hh >= 0 && hh < HH && ww >= 0 && ww < WW) {
                const int pix = hr * HC + (wc + kx);
                const int u0 = (pix * 4 + half * 2)     ^ (pix & 7);
                const int u1 = (pix * 4 + half * 2 + 1) ^ (pix & 7);
                uint4 a = Ks[u0], b = Ks[u1];
                float t = 0.f;
                t = fmaf(qf[0],  f16lo(a.x), t); t = fmaf(qf[1],  f16hi(a.x), t);
                t = fmaf(qf[2],  f16lo(a.y), t); t = fmaf(qf[3],  f16hi(a.y), t);
                t = fmaf(qf[4],  f16lo(a.z), t); t = fmaf(qf[5],  f16hi(a.z), t);
                t = fmaf(qf[6],  f16lo(a.w), t); t = fmaf(qf[7],  f16hi(a.w), t);
                t = fmaf(qf[8],  f16lo(b.x), t); t = fmaf(qf[9],  f16hi(b.x), t);
                t = fmaf(qf[10], f16lo(b.y), t); t = fmaf(qf[11], f16hi(b.y), t);
                t = fmaf(qf[12], f16lo(b.z), t); t = fmaf(qf[13], f16hi(b.z), t);
                t = fmaf(qf[14], f16lo(b.w), t); t = fmaf(qf[15], f16hi(b.w), t);
                s = t;
            } else {
                s = -1e30f;
            }
            sc[ky * 5 + kx] = s;
        }
    }
    // combine halves: lanes (2k, 2k+1) hold partials of the same pixel (VALU DPP)
    #pragma unroll
    for (int k = 0; k < 25; ++k) {
        float o = dpp_xor1(sc[k]);
        sc[k] = (sc[k] <= -1e29f) ? sc[k] : sc[k] + o;
    }

    float m = sc[0];
    #pragma unroll
    for (int k = 1; k < 25; ++k) m = fmaxf(m, sc[k]);
    float sum = 0.f;
    #pragma unroll
    for (int k = 0; k < 25; ++k) {
        float e = __expf(sc[k] - m);
        sc[k] = e;
        sum += e;
    }
    const float inv = 1.f / sum;

    // ---- PV: accumulate this thread's 16 dims ----
    float al[8], ah[8];
    #pragma unroll
    for (int i = 0; i < 8; ++i) { al[i] = 0.f; ah[i] = 0.f; }
    #pragma unroll
    for (int ky = 0; ky < 5; ++ky) {
        const int hh = h + ky - 2;
        if (hh < 0 || hh >= HH) continue;
        const int hr = tr + ky;
        #pragma unroll
        for (int kx = 0; kx < 5; ++kx) {
            const int ww = w + kx - 2;
            if (ww < 0 || ww >= WW) continue;
            const float a = sc[ky * 5 + kx];
            const int pix = hr * HC + (wc + kx);
            const int u0 = (pix * 4 + half * 2)     ^ (pix & 7);
            const int u1 = (pix * 4 + half * 2 + 1) ^ (pix & 7);
            uint4 x = Vs[u0], y = Vs[u1];
            al[0] = fmaf(a, f16lo(x.x), al[0]); ah[0] = fmaf(a, f16hi(x.x), ah[0]);
            al[1] = fmaf(a, f16lo(x.y), al[1]); ah[1] = fmaf(a, f16hi(x.y), ah[1]);
            al[2] = fmaf(a, f16lo(x.z), al[2]); ah[2] = fmaf(a, f16hi(x.z), ah[2]);
            al[3] = fmaf(a, f16lo(x.w), al[3]); ah[3] = fmaf(a, f16hi(x.w), ah[3]);
            al[4] = fmaf(a, f16lo(y.x), al[4]); ah[4] = fmaf(a, f16hi(y.x), ah[4]);
            al[5] = fmaf(a, f16lo(y.y), al[5]); ah[5] = fmaf(a, f16hi(y.y), ah[5]);
            al[6] = fmaf(a, f16lo(y.z), al[6]); ah[6] = fmaf(a, f16hi(y.z), ah[6]);
            al[7] = fmaf(a, f16lo(y.w), al[7]); ah[7] = fmaf(a, f16hi(y.w), ah[7]);
        }
    }

    // ---- store: dims half*16 .. half*16+15 ----
    float* Ob = out + ((size_t)(n * 8 + head) * 32 + half * 16) * HW + p;
    #pragma unroll
    for (int i = 0; i < 8; ++i) {
        Ob[(size_t)(2*i)   * HW] = al[i] * inv;
        Ob[(size_t)(2*i+1) * HW] = ah[i] * inv;
    }
}

// ---------------------------------------------------------------------------
extern "C" void kernel_launch(void* const* d_in, const int* in_sizes, int n_in,
                              void* d_out, int out_size, void* d_ws, size_t ws_size,
                              hipStream_t stream) {
    const float* x  = (const float*)d_in[0];   // (4, 256, 64, 64)
    const float* wq = (const float*)d_in[1];   // (768, 256)
    const float* bq = (const float*)d_in[2];   // (768,)
    float* out = (float*)d_out;                // (4, 256, 64, 64) fp32
    ushort16* qkv = (ushort16*)d_ws;           // fp16 [4][24][4096][32] = 25 MB

    dim3 g1(HW / 128, COUT / 128, 4);          // (32, 6, 4)
    qkv_gemm_kernel<<<g1, 256, 0, stream>>>(x, wq, bq, qkv);

    dim3 g2(32, 8, 4);                         // (16 h-tiles x 2 w-tiles, 8 heads, 4 n)
    attn_kernel<<<g2, 256, 0, stream>>>(qkv, out);
}